// Round 9
// baseline (200.117 us; speedup 1.0000x reference)
//
#include <hip/hip_runtime.h>

// ---------------------------------------------------------------------------
// MNIST Langevin Encoder — round 9: isolate the copy. Pure-stream copy kernel
// (plain ld/st, no winner read, no branch, 1 float4/thread — mimics the
// 7.2 TB/s runtime fill); langevin's scatter overwrites winner rows after
// (r4-proven semantics). zero only touched winner entries.
// Pipeline: prep -> zero_touched -> winner -> gemm1 -> gemm2 -> copy ->
//           langevin(+scatter)
// ---------------------------------------------------------------------------

#define ZD 64
#define NSTEPS 25
#define EPSI 0.01f
#define K1 784
#define K1P 800
#define HSTR 512   // padded hidden stride (bf16 h)

typedef __attribute__((ext_vector_type(8))) short short8;
typedef __attribute__((ext_vector_type(4))) float f32x4;

__device__ __forceinline__ unsigned short f2bf(float f) {
  union { float f; unsigned u; } v; v.f = f;
  return (unsigned short)((v.u + 0x7FFFu + ((v.u >> 16) & 1u)) >> 16);
}

__device__ __forceinline__ void gload_lds16(const void* g, void* l) {
  __builtin_amdgcn_global_load_lds(
      (const __attribute__((address_space(1))) void*)g,
      (__attribute__((address_space(3))) void*)l, 16, 0, 0);
}

// ---------------- prep: W1 -> w1b[512][800] bf16 ; [W21;W22] -> wout[128][512]
__global__ __launch_bounds__(256) void prep_kernel(
    const float* __restrict__ W1, const float* __restrict__ W21,
    const float* __restrict__ W22, short* __restrict__ W1b,
    short* __restrict__ Wout) {
  const int t = blockIdx.x * 256 + threadIdx.x;
  const int NW1 = 512 * (K1P / 8);   // 51200 chunks of 8
  if (t < NW1) {
    const int n = t / (K1P / 8), k0 = (t % (K1P / 8)) * 8;
    short8 v = {0, 0, 0, 0, 0, 0, 0, 0};
    if (n < 400 && k0 < K1) {
      const float* s = W1 + (long)n * K1 + k0;
#pragma unroll
      for (int e = 0; e < 8; e++) v[e] = (short)f2bf(s[e]);
    }
    *(short8*)(W1b + (long)t * 8) = v;
  } else {
    const int q = t - NW1;           // wout: 128*64 = 8192 chunks
    if (q < 128 * 64) {
      const int n = q / 64, k0 = (q % 64) * 8;
      short8 v = {0, 0, 0, 0, 0, 0, 0, 0};
      if (k0 < 400) {
        const float* s = (n < 64) ? (W21 + (long)n * 400 + k0)
                                  : (W22 + (long)(n - 64) * 400 + k0);
#pragma unroll
        for (int e = 0; e < 8; e++) v[e] = (short)f2bf(s[e]);
      }
      *(short8*)(Wout + (long)q * 8) = v;
    }
  }
}

// ---------------- zero only the winner entries we will read ----------------
__global__ __launch_bounds__(256) void zero_touched_kernel(
    const int* __restrict__ idx, int* __restrict__ winner, int B) {
  const int j = blockIdx.x * 256 + threadIdx.x;
  if (j < B) winner[idx[j]] = 0;     // races benign: all write 0
}

// ---------------- winner: last duplicate index wins ------------------------
__global__ __launch_bounds__(256) void winner_kernel(
    const int* __restrict__ idx, int* __restrict__ winner, int B) {
  const int j = blockIdx.x * 256 + threadIdx.x;
  if (j < B) atomicMax(&winner[idx[j]], j + 1);
}

// ---------------- GEMM1 (BM=32, BN=256, BK=32) -----------------------------
// bx>>1 = m-tile, bx&1 = n-half. 1024 blocks.
__global__ __launch_bounds__(256) void gemm1_kernel(
    const float* __restrict__ X, const short* __restrict__ W1b,
    const float* __restrict__ b1, unsigned short* __restrict__ H) {
  __shared__ short As[2 * 64 * 8];    // 2 KB, frag-major (2 row groups)
  __shared__ short Bs[16 * 64 * 8];   // 16 KB, frag-major (16 col groups)
  const int tid = threadIdx.x;
  const int w = tid >> 6;
  const int lane = tid & 63;
  const int m0 = (blockIdx.x >> 1) * 32;
  const int n0 = (blockIdx.x & 1) * 256;

  const f32x4 vzero = {0.f, 0.f, 0.f, 0.f};
  f32x4 acc[2][4];
#pragma unroll
  for (int i = 0; i < 2; i++)
#pragma unroll
    for (int j = 0; j < 4; j++) acc[i][j] = vzero;

  for (int k0 = 0; k0 < K1P; k0 += 32) {
    if (k0) __syncthreads();
    // A tile (32x32): reg-stage from fp32 x with on-the-fly cvt (tid<128).
    if (tid < 128) {
      const int row = m0 + (tid >> 6) * 16 + (lane & 15);
      const int gk = k0 + (lane >> 4) * 8;
      short8 av = {0, 0, 0, 0, 0, 0, 0, 0};
      if (gk < K1) {
        const float4 f0 = *(const float4*)(X + (long)row * K1 + gk);
        const float4 f1 = *(const float4*)(X + (long)row * K1 + gk + 4);
        av[0] = (short)f2bf(f0.x); av[1] = (short)f2bf(f0.y);
        av[2] = (short)f2bf(f0.z); av[3] = (short)f2bf(f0.w);
        av[4] = (short)f2bf(f1.x); av[5] = (short)f2bf(f1.y);
        av[6] = (short)f2bf(f1.z); av[7] = (short)f2bf(f1.w);
      }
      *(short8*)(As + (long)tid * 8) = av;
    }
    // B tile (256x32): global_load_lds, 4 groups per wave.
#pragma unroll
    for (int t = 0; t < 4; t++) {
      const int gn = w * 4 + t;
      const short* src = W1b + (long)(n0 + gn * 16 + (lane & 15)) * K1P +
                         k0 + (lane >> 4) * 8;
      gload_lds16(src, Bs + gn * 512);
    }
    __syncthreads();
    const short8* Ap = (const short8*)As;
    const short8* Bp = (const short8*)Bs;
    const short8 a0 = Ap[0 * 64 + lane];
    const short8 a1 = Ap[1 * 64 + lane];
#pragma unroll
    for (int j = 0; j < 4; j++) {
      const short8 b = Bp[(w * 4 + j) * 64 + lane];
      acc[0][j] = __builtin_amdgcn_mfma_f32_16x16x32_bf16(a0, b, acc[0][j], 0, 0, 0);
      acc[1][j] = __builtin_amdgcn_mfma_f32_16x16x32_bf16(a1, b, acc[1][j], 0, 0, 0);
    }
  }
  // epilogue: bias + relu + cvt -> bf16 h[row][col], stride 512
  const int colg = lane & 15;
  const int rowg = (lane >> 4) * 4;
#pragma unroll
  for (int j = 0; j < 4; j++) {
    const int col = n0 + w * 64 + j * 16 + colg;
    const float bias = (col < 400) ? b1[col] : 0.f;
#pragma unroll
    for (int i = 0; i < 2; i++) {
      const int rbase = m0 + i * 16 + rowg;
#pragma unroll
      for (int r = 0; r < 4; r++) {
        H[(long)(rbase + r) * HSTR + col] = f2bf(fmaxf(acc[i][j][r] + bias, 0.f));
      }
    }
  }
}

// ---------------- GEMM2 (BM=32, BN=128) ------------------------------------
__global__ __launch_bounds__(256) void gemm2_kernel(
    const unsigned short* __restrict__ H, const short* __restrict__ Wout,
    const float* __restrict__ b21, const float* __restrict__ b22,
    float* __restrict__ zloc, float* __restrict__ uarr) {
  __shared__ short As[2 * 64 * 8];   // 2 KB
  __shared__ short Bs[8 * 64 * 8];   // 8 KB
  const int tid = threadIdx.x;
  const int w = tid >> 6;
  const int lane = tid & 63;
  const int m0 = blockIdx.x * 32;

  const f32x4 vzero = {0.f, 0.f, 0.f, 0.f};
  f32x4 acc[2][2];
#pragma unroll
  for (int i = 0; i < 2; i++)
#pragma unroll
    for (int j = 0; j < 2; j++) acc[i][j] = vzero;

  for (int k0 = 0; k0 < HSTR; k0 += 32) {
    if (k0) __syncthreads();
    if (w < 2) {  // A groups 0..1 via waves 0..1
      const unsigned short* src = H + (long)(m0 + w * 16 + (lane & 15)) * HSTR +
                                  k0 + (lane >> 4) * 8;
      gload_lds16(src, As + w * 512);
    }
#pragma unroll
    for (int t = 0; t < 2; t++) {  // B groups, 2 per wave
      const int gn = w * 2 + t;
      const short* src = Wout + (long)(gn * 16 + (lane & 15)) * HSTR +
                         k0 + (lane >> 4) * 8;
      gload_lds16(src, Bs + gn * 512);
    }
    __syncthreads();
    const short8* Ap = (const short8*)As;
    const short8* Bp = (const short8*)Bs;
    const short8 a0 = Ap[0 * 64 + lane];
    const short8 a1 = Ap[1 * 64 + lane];
#pragma unroll
    for (int j = 0; j < 2; j++) {
      const short8 b = Bp[(w * 2 + j) * 64 + lane];
      acc[0][j] = __builtin_amdgcn_mfma_f32_16x16x32_bf16(a0, b, acc[0][j], 0, 0, 0);
      acc[1][j] = __builtin_amdgcn_mfma_f32_16x16x32_bf16(a1, b, acc[1][j], 0, 0, 0);
    }
  }
  const int colg = lane & 15;
  const int rowg = (lane >> 4) * 4;
  float* outp = (w < 2) ? zloc : uarr;
  const float* bp = (w < 2) ? b21 : b22;
#pragma unroll
  for (int j = 0; j < 2; j++) {
    const int col = (w & 1) * 32 + j * 16 + colg;   // 0..63 within zloc or u
    const float bias = bp[col];
#pragma unroll
    for (int i = 0; i < 2; i++) {
      const int rbase = m0 + i * 16 + rowg;
#pragma unroll
      for (int r = 0; r < 4; r++) {
        outp[(long)(rbase + r) * ZD + col] = acc[i][j][r] + bias;
      }
    }
  }
}

// ---------------- PURE stream copy: out_cache = cache ----------------------
// 1 float4/thread, plain load + plain store, no branches (mimic runtime fill).
__global__ __launch_bounds__(256) void copy_kernel(
    const f32x4* __restrict__ src, f32x4* __restrict__ dst) {
  const long e = (long)blockIdx.x * 256 + threadIdx.x;
  dst[e] = src[e];
}

// ---------------- Langevin + logq + winner-row scatter ---------------------
__global__ __launch_bounds__(256) void langevin_kernel(
    const float* __restrict__ zloc, const float* __restrict__ uarr,
    const float* __restrict__ cache, const int* __restrict__ idx,
    const float* __restrict__ noise, const int* __restrict__ winner,
    float* __restrict__ out_logq, float* __restrict__ out_z,
    float* __restrict__ out_cache, int B) {
  const int row = blockIdx.x * 4 + (threadIdx.x >> 6);
  const int lane = threadIdx.x & 63;
  const int i = idx[row];
  const float zl = zloc[(long)row * ZD + lane];
  const float uu = uarr[(long)row * ZD + lane];
  const float a = EPSI * expf(-2.f * uu);  // EPS * inv_var
  float z = cache[(long)i * ZD + lane];
  const float coef = sqrtf(2.f * EPSI);
  const float* np = noise + (long)row * ZD + lane;
  const long stride = (long)B * ZD;
#pragma unroll
  for (int s = 0; s < NSTEPS; s++) {
    z = z + a * (zl - z) + coef * np[(long)s * stride];
  }
  out_z[(long)row * ZD + lane] = z;
  // overwrite winner rows in new cache (copy already wrote cache there)
  if (winner[i] == row + 1) {
    out_cache[(long)i * ZD + lane] = z;
  }
  const float d = (z - zl) * expf(-uu);
  float t = -0.5f * d * d - uu - 0.91893853320467274178f;
#pragma unroll
  for (int off = 1; off < 64; off <<= 1) t += __shfl_xor(t, off);
  if (lane == 0) out_logq[row] = t;
}

extern "C" void kernel_launch(void* const* d_in, const int* in_sizes, int n_in,
                              void* d_out, int out_size, void* d_ws, size_t ws_size,
                              hipStream_t stream) {
  const float* x     = (const float*)d_in[0];
  const int*   idx   = (const int*)d_in[1];
  const float* W1    = (const float*)d_in[3];
  const float* b1    = (const float*)d_in[4];
  const float* W21   = (const float*)d_in[5];
  const float* b21   = (const float*)d_in[6];
  const float* W22   = (const float*)d_in[7];
  const float* b22   = (const float*)d_in[8];
  const float* cache = (const float*)d_in[9];
  const float* noise = (const float*)d_in[10];

  const int B  = in_sizes[1];            // 16384
  const int DS = in_sizes[9] / ZD;       // 1000000

  float* out_logq  = (float*)d_out;
  float* out_z     = out_logq + B;
  float* out_cache = out_z + (long)B * ZD;

  // workspace layout (~30.1 MB)
  unsigned short* h = (unsigned short*)d_ws;              // B*512 bf16
  short* w1b  = (short*)(h + (long)B * HSTR);             // 512*800 bf16
  short* wout = w1b + 512 * K1P;                          // 128*512 bf16
  float* zloc = (float*)(wout + 128 * HSTR);              // B*64 f32
  float* u    = zloc + (long)B * ZD;                      // B*64 f32
  int*   win  = (int*)(u + (long)B * ZD);                 // DS ints

  const int prep_chunks = 512 * (K1P / 8) + 128 * 64;
  prep_kernel<<<(prep_chunks + 255) / 256, 256, 0, stream>>>(W1, W21, W22, w1b, wout);
  zero_touched_kernel<<<(B + 255) / 256, 256, 0, stream>>>(idx, win, B);
  winner_kernel<<<(B + 255) / 256, 256, 0, stream>>>(idx, win, B);

  gemm1_kernel<<<(B / 32) * 2, 256, 0, stream>>>(x, w1b, b1, h);
  gemm2_kernel<<<B / 32, 256, 0, stream>>>(h, wout, b21, b22, zloc, u);

  const long n4 = (long)DS * (ZD / 4);                    // 16M float4
  copy_kernel<<<(unsigned)(n4 / 256), 256, 0, stream>>>(
      (const f32x4*)cache, (f32x4*)out_cache);

  langevin_kernel<<<B / 4, 256, 0, stream>>>(zloc, u, cache, idx, noise, win,
                                             out_logq, out_z, out_cache, B);
}

// Round 11
// 180.674 us; speedup vs baseline: 1.1076x; 1.1076x over previous
//
#include <hip/hip_runtime.h>

// ---------------------------------------------------------------------------
// MNIST Langevin Encoder — round 11: r10 with the copy-grid bug fixed.
//   * copy: 4 float4/thread, block covers 1024 float4, grid = 16M/1024 =
//     15625 EXACT (r10 used 4096/block -> 3906.25 truncated -> 64KB tail
//     never written -> Output 2 fail).
//   * gemm1 barrier-free (numerically verified by r10: outputs 0/1 passed).
// Pipeline: prep -> zero_touched -> winner -> gemm1 -> gemm2 -> copy ->
//           langevin(+scatter)
// ---------------------------------------------------------------------------

#define ZD 64
#define NSTEPS 25
#define EPSI 0.01f
#define K1 784
#define HSTR 512   // padded hidden stride (bf16 h)

typedef __attribute__((ext_vector_type(8))) short short8;
typedef __attribute__((ext_vector_type(4))) float f32x4;

__device__ __forceinline__ unsigned short f2bf(float f) {
  union { float f; unsigned u; } v; v.f = f;
  return (unsigned short)((v.u + 0x7FFFu + ((v.u >> 16) & 1u)) >> 16);
}

__device__ __forceinline__ void gload_lds16(const void* g, void* l) {
  __builtin_amdgcn_global_load_lds(
      (const __attribute__((address_space(1))) void*)g,
      (__attribute__((address_space(3))) void*)l, 16, 0, 0);
}

// ---------------- prep ------------------------------------------------------
// W1p: fragment-major pack of W1 for direct global->reg B-frags:
//   slot t = (g*25 + kc32)*64 + l  (short8)
//   value  = W1[g*16 + (l&15)][kc32*32 + (l>>4)*8 .. +8]   (zero-padded)
// Wout: [128][512] row-major bf16 (for gemm2's global_load_lds).
__global__ __launch_bounds__(256) void prep_kernel(
    const float* __restrict__ W1, const float* __restrict__ W21,
    const float* __restrict__ W22, short* __restrict__ W1p,
    short* __restrict__ Wout) {
  const int t = blockIdx.x * 256 + threadIdx.x;
  const int NW1 = 32 * 25 * 64;      // 51200 short8 slots
  if (t < NW1) {
    const int g = t / 1600;          // col group (16 cols)
    const int rem = t - g * 1600;
    const int kc32 = rem >> 6;
    const int l = rem & 63;
    const int col = g * 16 + (l & 15);
    const int k = kc32 * 32 + (l >> 4) * 8;
    short8 v = {0, 0, 0, 0, 0, 0, 0, 0};
    if (col < 400 && k + 8 <= K1) {
      const float* s = W1 + (long)col * K1 + k;
#pragma unroll
      for (int e = 0; e < 8; e++) v[e] = (short)f2bf(s[e]);
    }
    *(short8*)(W1p + (long)t * 8) = v;
  } else {
    const int q = t - NW1;           // wout: 128*64 = 8192 chunks
    if (q < 128 * 64) {
      const int n = q / 64, k0 = (q % 64) * 8;
      short8 v = {0, 0, 0, 0, 0, 0, 0, 0};
      if (k0 < 400) {
        const float* s = (n < 64) ? (W21 + (long)n * 400 + k0)
                                  : (W22 + (long)(n - 64) * 400 + k0);
#pragma unroll
        for (int e = 0; e < 8; e++) v[e] = (short)f2bf(s[e]);
      }
      *(short8*)(Wout + (long)q * 8) = v;
    }
  }
}

// ---------------- zero only the winner entries we will read ----------------
__global__ __launch_bounds__(256) void zero_touched_kernel(
    const int* __restrict__ idx, int* __restrict__ winner, int B) {
  const int j = blockIdx.x * 256 + threadIdx.x;
  if (j < B) winner[idx[j]] = 0;     // races benign: all write 0
}

// ---------------- winner: last duplicate index wins ------------------------
__global__ __launch_bounds__(256) void winner_kernel(
    const int* __restrict__ idx, int* __restrict__ winner, int B) {
  const int j = blockIdx.x * 256 + threadIdx.x;
  if (j < B) atomicMax(&winner[idx[j]], j + 1);
}

// ---------------- GEMM1: barrier-free K-loop -------------------------------
// block: 64 rows x 512 cols, 8 waves (wave w -> cols w*64..w*64+63).
// A-LDS slots (short8): slot = (kc32*4 + rg)*64 + lanepart, holding
//   A[row = rg*16 + (lanepart&15)][kc32*32 + (lanepart>>4)*8 .. +8]
// Staged linearly (slot = tid + iter*512) -> conflict-free ds_write_b128.
__global__ __launch_bounds__(512, 2) void gemm1_kernel(
    const float* __restrict__ X, const short* __restrict__ W1p,
    const float* __restrict__ b1, unsigned short* __restrict__ H) {
  __shared__ short As[6400 * 8];     // 100 KB
  const int tid = threadIdx.x;
  const int w = tid >> 6;
  const int lane = tid & 63;
  const int m0 = blockIdx.x * 64;

  // ---- stage A once ----
  for (int slot = tid; slot < 6400; slot += 512) {
    const int lp = slot & 63;
    const int chunk = slot >> 6;         // kc32*4 + rg
    const int rg = chunk & 3;
    const int kc32 = chunk >> 2;
    const int row = rg * 16 + (lp & 15);
    const int k = kc32 * 32 + (lp >> 4) * 8;
    short8 av = {0, 0, 0, 0, 0, 0, 0, 0};
    if (k + 8 <= K1) {
      const float4 f0 = *(const float4*)(X + (long)(m0 + row) * K1 + k);
      const float4 f1 = *(const float4*)(X + (long)(m0 + row) * K1 + k + 4);
      av[0] = (short)f2bf(f0.x); av[1] = (short)f2bf(f0.y);
      av[2] = (short)f2bf(f0.z); av[3] = (short)f2bf(f0.w);
      av[4] = (short)f2bf(f1.x); av[5] = (short)f2bf(f1.y);
      av[6] = (short)f2bf(f1.z); av[7] = (short)f2bf(f1.w);
    }
    *(short8*)(As + (long)slot * 8) = av;
  }
  __syncthreads();   // the ONLY barrier

  const f32x4 vzero = {0.f, 0.f, 0.f, 0.f};
  f32x4 acc[4][4];
#pragma unroll
  for (int i = 0; i < 4; i++)
#pragma unroll
    for (int j = 0; j < 4; j++) acc[i][j] = vzero;

  const short8* Ap = (const short8*)As;
  const short8* Bp = (const short8*)W1p;
  for (int kc = 0; kc < 25; kc++) {
    short8 a[4], b[4];
#pragma unroll
    for (int rg = 0; rg < 4; rg++) a[rg] = Ap[(kc * 4 + rg) * 64 + lane];
#pragma unroll
    for (int j = 0; j < 4; j++) b[j] = Bp[((w * 4 + j) * 25 + kc) * 64 + lane];
#pragma unroll
    for (int rg = 0; rg < 4; rg++)
#pragma unroll
      for (int j = 0; j < 4; j++)
        acc[rg][j] = __builtin_amdgcn_mfma_f32_16x16x32_bf16(a[rg], b[j], acc[rg][j], 0, 0, 0);
  }

  // epilogue: bias + relu + cvt -> bf16 h[row][col], stride 512
  const int colg = lane & 15;
  const int rowg = (lane >> 4) * 4;
#pragma unroll
  for (int j = 0; j < 4; j++) {
    const int col = w * 64 + j * 16 + colg;
    const float bias = (col < 400) ? b1[col] : 0.f;
#pragma unroll
    for (int rg = 0; rg < 4; rg++) {
      const int rbase = m0 + rg * 16 + rowg;
#pragma unroll
      for (int r = 0; r < 4; r++) {
        H[(long)(rbase + r) * HSTR + col] = f2bf(fmaxf(acc[rg][j][r] + bias, 0.f));
      }
    }
  }
}

// ---------------- GEMM2 (BM=32, BN=128) — unchanged ------------------------
__global__ __launch_bounds__(256) void gemm2_kernel(
    const unsigned short* __restrict__ H, const short* __restrict__ Wout,
    const float* __restrict__ b21, const float* __restrict__ b22,
    float* __restrict__ zloc, float* __restrict__ uarr) {
  __shared__ short As[2 * 64 * 8];   // 2 KB
  __shared__ short Bs[8 * 64 * 8];   // 8 KB
  const int tid = threadIdx.x;
  const int w = tid >> 6;
  const int lane = tid & 63;
  const int m0 = blockIdx.x * 32;

  const f32x4 vzero = {0.f, 0.f, 0.f, 0.f};
  f32x4 acc[2][2];
#pragma unroll
  for (int i = 0; i < 2; i++)
#pragma unroll
    for (int j = 0; j < 2; j++) acc[i][j] = vzero;

  for (int k0 = 0; k0 < HSTR; k0 += 32) {
    if (k0) __syncthreads();
    if (w < 2) {  // A groups 0..1 via waves 0..1
      const unsigned short* src = H + (long)(m0 + w * 16 + (lane & 15)) * HSTR +
                                  k0 + (lane >> 4) * 8;
      gload_lds16(src, As + w * 512);
    }
#pragma unroll
    for (int t = 0; t < 2; t++) {  // B groups, 2 per wave
      const int gn = w * 2 + t;
      const short* src = Wout + (long)(gn * 16 + (lane & 15)) * HSTR +
                         k0 + (lane >> 4) * 8;
      gload_lds16(src, Bs + gn * 512);
    }
    __syncthreads();
    const short8* Ap = (const short8*)As;
    const short8* Bp = (const short8*)Bs;
    const short8 a0 = Ap[0 * 64 + lane];
    const short8 a1 = Ap[1 * 64 + lane];
#pragma unroll
    for (int j = 0; j < 2; j++) {
      const short8 b = Bp[(w * 2 + j) * 64 + lane];
      acc[0][j] = __builtin_amdgcn_mfma_f32_16x16x32_bf16(a0, b, acc[0][j], 0, 0, 0);
      acc[1][j] = __builtin_amdgcn_mfma_f32_16x16x32_bf16(a1, b, acc[1][j], 0, 0, 0);
    }
  }
  const int colg = lane & 15;
  const int rowg = (lane >> 4) * 4;
  float* outp = (w < 2) ? zloc : uarr;
  const float* bp = (w < 2) ? b21 : b22;
#pragma unroll
  for (int j = 0; j < 2; j++) {
    const int col = (w & 1) * 32 + j * 16 + colg;   // 0..63 within zloc or u
    const float bias = bp[col];
#pragma unroll
    for (int i = 0; i < 2; i++) {
      const int rbase = m0 + i * 16 + rowg;
#pragma unroll
      for (int r = 0; r < 4; r++) {
        outp[(long)(rbase + r) * ZD + col] = acc[i][j][r] + bias;
      }
    }
  }
}

// ---------------- stream copy: 4 float4/thread, exact grid -----------------
// block covers 1024 float4; 16,000,000 / 1024 = 15625 blocks exactly.
__global__ __launch_bounds__(256) void copy_kernel(
    const f32x4* __restrict__ src, f32x4* __restrict__ dst) {
  const long base = (long)blockIdx.x * 1024 + threadIdx.x;
  f32x4 v0 = src[base];
  f32x4 v1 = src[base + 256];
  f32x4 v2 = src[base + 512];
  f32x4 v3 = src[base + 768];
  dst[base] = v0;
  dst[base + 256] = v1;
  dst[base + 512] = v2;
  dst[base + 768] = v3;
}

// ---------------- Langevin + logq + winner-row scatter ---------------------
__global__ __launch_bounds__(256) void langevin_kernel(
    const float* __restrict__ zloc, const float* __restrict__ uarr,
    const float* __restrict__ cache, const int* __restrict__ idx,
    const float* __restrict__ noise, const int* __restrict__ winner,
    float* __restrict__ out_logq, float* __restrict__ out_z,
    float* __restrict__ out_cache, int B) {
  const int row = blockIdx.x * 4 + (threadIdx.x >> 6);
  const int lane = threadIdx.x & 63;
  const int i = idx[row];
  const float zl = zloc[(long)row * ZD + lane];
  const float uu = uarr[(long)row * ZD + lane];
  const float a = EPSI * expf(-2.f * uu);  // EPS * inv_var
  float z = cache[(long)i * ZD + lane];
  const float coef = sqrtf(2.f * EPSI);
  const float* np = noise + (long)row * ZD + lane;
  const long stride = (long)B * ZD;
#pragma unroll
  for (int s = 0; s < NSTEPS; s++) {
    z = z + a * (zl - z) + coef * np[(long)s * stride];
  }
  out_z[(long)row * ZD + lane] = z;
  // overwrite winner rows in new cache (copy already wrote cache there)
  if (winner[i] == row + 1) {
    out_cache[(long)i * ZD + lane] = z;
  }
  const float d = (z - zl) * expf(-uu);
  float t = -0.5f * d * d - uu - 0.91893853320467274178f;
#pragma unroll
  for (int off = 1; off < 64; off <<= 1) t += __shfl_xor(t, off);
  if (lane == 0) out_logq[row] = t;
}

extern "C" void kernel_launch(void* const* d_in, const int* in_sizes, int n_in,
                              void* d_out, int out_size, void* d_ws, size_t ws_size,
                              hipStream_t stream) {
  const float* x     = (const float*)d_in[0];
  const int*   idx   = (const int*)d_in[1];
  const float* W1    = (const float*)d_in[3];
  const float* b1    = (const float*)d_in[4];
  const float* W21   = (const float*)d_in[5];
  const float* b21   = (const float*)d_in[6];
  const float* W22   = (const float*)d_in[7];
  const float* b22   = (const float*)d_in[8];
  const float* cache = (const float*)d_in[9];
  const float* noise = (const float*)d_in[10];

  const int B  = in_sizes[1];            // 16384
  const int DS = in_sizes[9] / ZD;       // 1000000

  float* out_logq  = (float*)d_out;
  float* out_z     = out_logq + B;
  float* out_cache = out_z + (long)B * ZD;

  // workspace layout (~25 MB)
  unsigned short* h = (unsigned short*)d_ws;              // B*512 bf16
  short* w1p  = (short*)(h + (long)B * HSTR);             // 32*25*64*8 bf16 (800KB)
  short* wout = w1p + 32 * 25 * 64 * 8;                   // 128*512 bf16
  float* zloc = (float*)(wout + 128 * HSTR);              // B*64 f32
  float* u    = zloc + (long)B * ZD;                      // B*64 f32
  int*   win  = (int*)(u + (long)B * ZD);                 // DS ints

  const int prep_chunks = 32 * 25 * 64 + 128 * 64;        // 59392
  prep_kernel<<<(prep_chunks + 255) / 256, 256, 0, stream>>>(W1, W21, W22, w1p, wout);
  zero_touched_kernel<<<(B + 255) / 256, 256, 0, stream>>>(idx, win, B);
  winner_kernel<<<(B + 255) / 256, 256, 0, stream>>>(idx, win, B);

  gemm1_kernel<<<B / 64, 512, 0, stream>>>(x, w1p, b1, h);
  gemm2_kernel<<<B / 32, 256, 0, stream>>>(h, wout, b21, b22, zloc, u);

  const long n4 = (long)DS * (ZD / 4);                    // 16M float4
  copy_kernel<<<(unsigned)(n4 / 1024), 256, 0, stream>>>(
      (const f32x4*)cache, (f32x4*)out_cache);

  langevin_kernel<<<B / 4, 256, 0, stream>>>(zloc, u, cache, idx, noise, win,
                                             out_logq, out_z, out_cache, B);
}